// Round 12
// baseline (427.974 us; speedup 1.0000x reference)
//
#include <hip/hip_runtime.h>

typedef unsigned short u16;
typedef unsigned int u32;
typedef unsigned long long u64;
typedef __bf16 bf16x8 __attribute__((ext_vector_type(8)));
typedef float f32x4 __attribute__((ext_vector_type(4)));
typedef int i32x4 __attribute__((ext_vector_type(4)));

__device__ __forceinline__ float b2f(u16 u) {
    unsigned int x = ((unsigned int)u) << 16;
    return __builtin_bit_cast(float, x);
}
__device__ __forceinline__ u16 f2b(float f) {
    unsigned int u = __builtin_bit_cast(unsigned int, f);
    unsigned int r = (u + 0x7FFFu + ((u >> 16) & 1u)) >> 16;
    return (u16)r;
}
__device__ __forceinline__ unsigned int pack2(float a, float b) {
    return (unsigned int)f2b(a) | ((unsigned int)f2b(b) << 16);
}
__device__ __forceinline__ float fast_rcp(float x) { return __builtin_amdgcn_rcpf(x); }
__device__ __forceinline__ float fast_tanh(float x) {
    float e = __expf(2.f * x);
    return 1.f - 2.f * fast_rcp(e + 1.f);
}
__device__ __forceinline__ float fast_sig(float x) {
    float e = __expf(-x);
    return fast_rcp(1.f + e);
}

#define FLAG_STRIDE 32
#define NW 32  // LSTM workers, 16 k-cols each

__device__ __forceinline__ u32 ld_agent(const u32* p) {
    return __hip_atomic_load(p, __ATOMIC_RELAXED, __HIP_MEMORY_SCOPE_AGENT);
}
__device__ __forceinline__ void st_agent(u32* p, u32 v) {
    __hip_atomic_store(p, v, __ATOMIC_RELAXED, __HIP_MEMORY_SCOPE_AGENT);
}
// XCD-local (same-L2) data ops: sc0 = bypass L1 (CDNA L1 is write-through)
__device__ __forceinline__ void st16_sc0(void* p, i32x4 v) {
    asm volatile("global_store_dwordx4 %0, %1, off sc0" :: "v"(p), "v"(v) : "memory");
}
__device__ __forceinline__ i32x4 ld16_sc0(const void* p) {
    i32x4 v;
    asm volatile("global_load_dwordx4 %0, %1, off sc0" : "=v"(v) : "v"(p) : "memory");
    return v;
}
__device__ __forceinline__ void waitvm0_dep8(i32x4* v) {
    asm volatile("s_waitcnt vmcnt(0)"
                 : "+v"(v[0]), "+v"(v[1]), "+v"(v[2]), "+v"(v[3]),
                   "+v"(v[4]), "+v"(v[5]), "+v"(v[6]), "+v"(v[7]));
}

// ---------------- fused prep: casts + xfull + 4x transpose + ctrl zero ------
__launch_bounds__(256)
__global__ void k_prep(const float* __restrict__ attn_mem, u16* __restrict__ amem_bf,
                       const float* __restrict__ w_ih, u16* __restrict__ wih_bf,
                       const float* __restrict__ w_hh, u16* __restrict__ whh_bf,
                       const float* __restrict__ lstm_in, const float* __restrict__ init_i,
                       u16* __restrict__ xfull,
                       const float* s0, const float* s1, const float* s2, const float* s3,
                       u16* d0, u16* d1, u16* d2, u16* d3,
                       u32* __restrict__ flags, u32* __restrict__ ctrl) {
    __shared__ float tile[32][33];
    int bid = blockIdx.x;
    int tid = threadIdx.x;
    if (bid == 0) {
        if (tid < NW) st_agent(&flags[tid * FLAG_STRIDE], 0u);
        if (tid >= 64 && tid < 72) st_agent(&ctrl[(tid - 64) * 32], 0u);
    }
    if (bid < 4096) {
        const float* s;
        u16* d;
        int i;
        if (bid < 2048) { s = attn_mem; d = amem_bf; i = bid * 256 + tid; }
        else if (bid < 3072) { s = w_ih; d = wih_bf; i = (bid - 2048) * 256 + tid; }
        else { s = w_hh; d = whh_bf; i = (bid - 3072) * 256 + tid; }
        float4 a = ((const float4*)s)[i];
        uint2 p;
        p.x = pack2(a.x, a.y);
        p.y = pack2(a.z, a.w);
        ((uint2*)d)[i] = p;
    } else if (bid < 4608) {
        int idx = (bid - 4096) * 256 + tid;
        int c = idx & 127;
        int t = (idx >> 7) & 31;
        int b = idx >> 12;
        const float4* src = (t == 0) ? ((const float4*)init_i) + c
                                     : ((const float4*)lstm_in) + ((b * 31 + (t - 1)) * 128 + c);
        float4 a = *src;
        uint2 p;
        p.x = pack2(a.x, a.y);
        p.y = pack2(a.z, a.w);
        ((uint2*)xfull)[idx] = p;
    } else {
        int local = bid - 4608;
        int z = local >> 8, rem = local & 255;
        int by = (rem >> 4) * 32, bx = (rem & 15) * 32;
        const float* s;
        u16* d;
        switch (z) {
            case 0: s = s0; d = d0; break;
            case 1: s = s1; d = d1; break;
            case 2: s = s2; d = d2; break;
            default: s = s3; d = d3; break;
        }
        int tx = tid & 31, ty = tid >> 5;
        for (int i = 0; i < 32; i += 8) tile[ty + i][tx] = s[(by + ty + i) * 512 + bx + tx];
        __syncthreads();
        for (int i = 0; i < 32; i += 8) d[(bx + ty + i) * 512 + by + tx] = f2b(tile[tx][ty + i]);
    }
}

// ---------------- xw GEMM: 512 blocks --------------------------------------
__launch_bounds__(256)
__global__ void k_xw(const u16* __restrict__ xfull, const u16* __restrict__ wih,
                     float* __restrict__ xw,
                     const float* __restrict__ b_ih, const float* __restrict__ b_hh) {
    __shared__ u16 As[64][40];
    __shared__ u16 Bs[64][40];
    int id = blockIdx.x;
    int m0 = (id >> 5) * 64, n0 = (id & 31) * 64;
    int tid = threadIdx.x;
    int lane = tid & 63, w = tid >> 6;
    int wm = w >> 1, wn = w & 1;
    int l15 = lane & 15, quad = lane >> 4;
    f32x4 acc[2][2] = {};
    int ar = tid >> 2, ac = (tid & 3) * 8;
    const u16* Ap = xfull + (m0 + ar) * 512 + ac;
    const u16* Bp = wih + (n0 + ar) * 512 + ac;
    for (int kt = 0; kt < 16; ++kt) {
        uint4 av = *(const uint4*)(Ap + kt * 32);
        uint4 bv = *(const uint4*)(Bp + kt * 32);
        __syncthreads();
        *(uint4*)&As[ar][ac] = av;
        *(uint4*)&Bs[ar][ac] = bv;
        __syncthreads();
        bf16x8 a0 = *(const bf16x8*)&As[wm * 32 + l15][quad * 8];
        bf16x8 a1 = *(const bf16x8*)&As[wm * 32 + 16 + l15][quad * 8];
        bf16x8 b0 = *(const bf16x8*)&Bs[wn * 32 + l15][quad * 8];
        bf16x8 b1 = *(const bf16x8*)&Bs[wn * 32 + 16 + l15][quad * 8];
        acc[0][0] = __builtin_amdgcn_mfma_f32_16x16x32_bf16(a0, b0, acc[0][0], 0, 0, 0);
        acc[0][1] = __builtin_amdgcn_mfma_f32_16x16x32_bf16(a0, b1, acc[0][1], 0, 0, 0);
        acc[1][0] = __builtin_amdgcn_mfma_f32_16x16x32_bf16(a1, b0, acc[1][0], 0, 0, 0);
        acc[1][1] = __builtin_amdgcn_mfma_f32_16x16x32_bf16(a1, b1, acc[1][1], 0, 0, 0);
    }
    for (int ai = 0; ai < 2; ++ai)
        for (int bi = 0; bi < 2; ++bi) {
            int row = m0 + wm * 32 + ai * 16 + quad * 4;
            int col = n0 + wn * 32 + bi * 16 + l15;
            float bias = b_ih[col] + b_hh[col];
            for (int r = 0; r < 4; ++r) xw[(row + r) * 2048 + col] = acc[ai][bi][r] + bias;
        }
}

// ---------------- standalone GEMM for nq @ WqT_attn ------------------------
__launch_bounds__(256)
__global__ void k_gemm(const u16* __restrict__ A, const u16* __restrict__ Bt,
                       float* __restrict__ C, int GN) {
    __shared__ u16 As[64][40];
    __shared__ u16 Bs[64][40];
    int m0 = blockIdx.y * 64, n0 = blockIdx.x * 64;
    int tid = threadIdx.x;
    int lane = tid & 63, w = tid >> 6;
    int wm = w >> 1, wn = w & 1;
    int l15 = lane & 15, quad = lane >> 4;
    f32x4 acc[2][2] = {};
    int ar = tid >> 2, ac = (tid & 3) * 8;
    const u16* Ap = A + (m0 + ar) * 512 + ac;
    const u16* Bp = Bt + (n0 + ar) * 512 + ac;
    for (int kt = 0; kt < 16; ++kt) {
        uint4 av = *(const uint4*)(Ap + kt * 32);
        uint4 bv = *(const uint4*)(Bp + kt * 32);
        __syncthreads();
        *(uint4*)&As[ar][ac] = av;
        *(uint4*)&Bs[ar][ac] = bv;
        __syncthreads();
        bf16x8 a0 = *(const bf16x8*)&As[wm * 32 + l15][quad * 8];
        bf16x8 a1 = *(const bf16x8*)&As[wm * 32 + 16 + l15][quad * 8];
        bf16x8 b0 = *(const bf16x8*)&Bs[wn * 32 + l15][quad * 8];
        bf16x8 b1 = *(const bf16x8*)&Bs[wn * 32 + 16 + l15][quad * 8];
        acc[0][0] = __builtin_amdgcn_mfma_f32_16x16x32_bf16(a0, b0, acc[0][0], 0, 0, 0);
        acc[0][1] = __builtin_amdgcn_mfma_f32_16x16x32_bf16(a0, b1, acc[0][1], 0, 0, 0);
        acc[1][0] = __builtin_amdgcn_mfma_f32_16x16x32_bf16(a1, b0, acc[1][0], 0, 0, 0);
        acc[1][1] = __builtin_amdgcn_mfma_f32_16x16x32_bf16(a1, b1, acc[1][1], 0, 0, 0);
    }
    for (int ai = 0; ai < 2; ++ai)
        for (int bi = 0; bi < 2; ++bi) {
            int row = m0 + wm * 32 + ai * 16 + quad * 4;
            int col = n0 + wn * 32 + bi * 16 + l15;
            for (int r = 0; r < 4; ++r) C[(row + r) * GN + col] = acc[ai][bi][r];
        }
}

// ---------------- LSTM worker: 16 k-cols, data path templated --------------
// Flags ALWAYS agent-scope (hang-proof); LOCAL switches only the h data path.
template <bool LOCAL>
__device__ __forceinline__ void lstm_worker(int slot,
        u16 (*Bw0)[520], u16 (*Bw1)[520], u16 (*Ah)[520], u16 (*Wq)[520],
        float (*gl)[66], u16 (*gb)[16],
        const u16* __restrict__ whh, const float* __restrict__ xw,
        const float* __restrict__ init_h, const float* __restrict__ init_c,
        const u16* __restrict__ wqT, float* __restrict__ qbuf,
        char* __restrict__ hbuf, u32* __restrict__ flags) {
    int tid = threadIdx.x;
    int lane = tid & 63, w = tid >> 6;
    int l15 = lane & 15, quad = lane >> 4;
    int k0 = slot * 16;
    // stage w_hh slice: virtual col c=gate*16+kl <-> w_hh row gate*512+k0+kl
    {
        int r = tid >> 2, s4 = tid & 3;
        u16 (*BwT)[520] = (r < 32) ? Bw0 : Bw1;
        int rr = r & 31;
        int j = (r >> 4) * 512 + k0 + (r & 15);
        const uint4* src = (const uint4*)(whh + j * 512);
        for (int i = 0; i < 16; ++i)
            *(uint4*)&BwT[rr][(s4 * 16 + i) * 8] = src[s4 * 16 + i];
    }
    // stage Wq (16 rows = q2 output cols k0..k0+15)
    {
        int r = tid >> 4, s16 = tid & 15;
        const uint4* src = (const uint4*)(wqT + (k0 + r) * 512);
        for (int i = 0; i < 4; ++i)
            *(uint4*)&Wq[r][(s16 + 16 * i) * 8] = src[s16 + 16 * i];
    }
    int row = tid >> 3, seg = tid & 7;
    for (int i = 0; i < 8; ++i) {
        int col = (seg + 8 * i) * 8;
        float4 f0 = *(const float4*)(init_h + col);
        float4 f1 = *(const float4*)(init_h + col + 4);
        uint4 p;
        p.x = pack2(f0.x, f0.y);
        p.y = pack2(f0.z, f0.w);
        p.z = pack2(f1.x, f1.y);
        p.w = pack2(f1.z, f1.w);
        *(uint4*)&Ah[row][col] = p;
    }
    int kl0 = seg * 2;
    float c0 = init_c[k0 + kl0], c1 = init_c[k0 + kl0 + 1];
    float2 xc[4];
    {
        const float* p = xw + (row << 5) * 2048 + k0 + kl0;
        for (int g = 0; g < 4; ++g) xc[g] = *(const float2*)(p + g * 512);
    }
    int mw = w >> 1, ni = w & 1;
    u16 (*BwH)[520] = ni ? Bw1 : Bw0;
    __syncthreads();
    for (int t = 0; t < 32; ++t) {
        f32x4 acc0 = {}, acc1 = {};
#pragma unroll
        for (int kc = 0; kc < 16; ++kc) {
            bf16x8 af = *(const bf16x8*)&Ah[mw * 16 + l15][kc * 32 + quad * 8];
            bf16x8 bf0 = *(const bf16x8*)&BwH[l15][kc * 32 + quad * 8];
            bf16x8 bf1 = *(const bf16x8*)&BwH[16 + l15][kc * 32 + quad * 8];
            acc0 = __builtin_amdgcn_mfma_f32_16x16x32_bf16(af, bf0, acc0, 0, 0, 0);
            acc1 = __builtin_amdgcn_mfma_f32_16x16x32_bf16(af, bf1, acc1, 0, 0, 0);
        }
        {
            int r0 = mw * 16 + quad * 4;
            for (int r = 0; r < 4; ++r) {
                gl[r0 + r][ni * 32 + l15] = acc0[r];
                gl[r0 + r][ni * 32 + 16 + l15] = acc1[r];
            }
        }
        __syncthreads();  // #1
        {
            float gi = gl[row][kl0] + xc[0].x;
            float gf = gl[row][16 + kl0] + xc[1].x;
            float gg = gl[row][32 + kl0] + xc[2].x;
            float go = gl[row][48 + kl0] + xc[3].x;
            float cn = fast_sig(gf) * c0 + fast_sig(gi) * fast_tanh(gg);
            c0 = cn;
            gb[row][kl0] = f2b(fast_sig(go) * fast_tanh(cn));
            gi = gl[row][kl0 + 1] + xc[0].y;
            gf = gl[row][16 + kl0 + 1] + xc[1].y;
            gg = gl[row][32 + kl0 + 1] + xc[2].y;
            go = gl[row][48 + kl0 + 1] + xc[3].y;
            cn = fast_sig(gf) * c1 + fast_sig(gi) * fast_tanh(gg);
            c1 = cn;
            gb[row][kl0 + 1] = f2b(fast_sig(go) * fast_tanh(cn));
        }
        __syncthreads();  // #2
        char* hb_base = hbuf + (t & 1) * (NW * 1024);
        if (tid < 64) {
            int b2 = tid >> 1, half = tid & 1;
            char* dst = hb_base + slot * 1024 + b2 * 32 + half * 16;
            if (LOCAL) {
                st16_sc0(dst, *(const i32x4*)&gb[b2][half * 8]);
            } else {
                const u64* sv = (const u64*)&gb[b2][half * 8];
                u64* d64 = (u64*)dst;
                __hip_atomic_store(&d64[0], sv[0], __ATOMIC_RELAXED, __HIP_MEMORY_SCOPE_AGENT);
                __hip_atomic_store(&d64[1], sv[1], __ATOMIC_RELAXED, __HIP_MEMORY_SCOPE_AGENT);
            }
            __builtin_amdgcn_s_waitcnt(0);  // h stores acked before flag store
            if (tid == 0) st_agent(&flags[slot * FLAG_STRIDE], (u32)(t + 1));
            for (;;) {
                u32 f = 0xFFFFFFFFu;
                if (tid < NW) f = ld_agent(&flags[tid * FLAG_STRIDE]);
                if (__ballot(f > (u32)t) == ~0ull) break;
                __builtin_amdgcn_s_sleep(1);
            }
        } else if (t > 0 && w <= 2) {
            // q2 slice for time t-1 (Ah = h(t) = query[t-1]) on waves 1-2
            f32x4 a2 = {};
#pragma unroll
            for (int kc = 0; kc < 16; ++kc) {
                bf16x8 af = *(const bf16x8*)&Ah[(w - 1) * 16 + l15][kc * 32 + quad * 8];
                bf16x8 bq = *(const bf16x8*)&Wq[l15][kc * 32 + quad * 8];
                a2 = __builtin_amdgcn_mfma_f32_16x16x32_bf16(af, bq, a2, 0, 0, 0);
            }
            int bb = (w - 1) * 16 + quad * 4;
            for (int r = 0; r < 4; ++r)
                qbuf[(((bb + r) << 5) + (t - 1)) * 512 + k0 + l15] = a2[r];
        }
        __syncthreads();  // #3
        int tn = (t < 31) ? t + 1 : 31;
        float2 xn[4];
        {
            const float* p = xw + ((row << 5) + tn) * 2048 + k0 + kl0;
            for (int g = 0; g < 4; ++g) xn[g] = *(const float2*)(p + g * 512);
        }
        if (LOCAL) {
            i32x4 v[8];
#pragma unroll
            for (int i = 0; i < 8; ++i) {
                int idx = seg + 8 * i;
                v[i] = ld16_sc0(hb_base + (idx >> 1) * 1024 + row * 32 + (idx & 1) * 16);
            }
            waitvm0_dep8(v);  // dependency-tied vmcnt(0): no reorder hazard
#pragma unroll
            for (int i = 0; i < 8; ++i) {
                int idx = seg + 8 * i;
                *(i32x4*)&Ah[row][(idx >> 1) * 16 + (idx & 1) * 8] = v[i];
            }
        } else {
#pragma unroll
            for (int i = 0; i < 8; ++i) {
                int idx = seg + 8 * i;
                u64* sp = (u64*)(hb_base + (idx >> 1) * 1024 + row * 32 + (idx & 1) * 16);
                u64 v0 = __hip_atomic_load(&sp[0], __ATOMIC_RELAXED, __HIP_MEMORY_SCOPE_AGENT);
                u64 v1 = __hip_atomic_load(&sp[1], __ATOMIC_RELAXED, __HIP_MEMORY_SCOPE_AGENT);
                u64* d = (u64*)&Ah[row][(idx >> 1) * 16 + (idx & 1) * 8];
                d[0] = v0;
                d[1] = v1;
            }
        }
        __syncthreads();  // #4
        for (int g = 0; g < 4; ++g) xc[g] = xn[g];
    }
    // epilogue: q2 for t=31 (Ah = h(32) = query[31])
    if (w == 1 || w == 2) {
        f32x4 a2 = {};
#pragma unroll
        for (int kc = 0; kc < 16; ++kc) {
            bf16x8 af = *(const bf16x8*)&Ah[(w - 1) * 16 + l15][kc * 32 + quad * 8];
            bf16x8 bq = *(const bf16x8*)&Wq[l15][kc * 32 + quad * 8];
            a2 = __builtin_amdgcn_mfma_f32_16x16x32_bf16(af, bq, a2, 0, 0, 0);
        }
        int bb = (w - 1) * 16 + quad * 4;
        for (int r = 0; r < 4; ++r)
            qbuf[(((bb + r) << 5) + 31) * 512 + k0 + l15] = a2[r];
    }
}

// ---------------- feat worker: pulls 8-tile batches from queue -------------
__device__ __forceinline__ void feat_worker(u16 (*As)[40], u16 (*Bs)[40],
        u32* __restrict__ ctrl, const u16* __restrict__ amem,
        const u16* __restrict__ Bh, const u16* __restrict__ Ba,
        u16* __restrict__ Ch, u16* __restrict__ Ca, int* sh_tile) {
    int tid = threadIdx.x;
    int lane = tid & 63, w = tid >> 6;
    int wm = w >> 1, wn = w & 1;
    int l15 = lane & 15, quad = lane >> 4;
    for (;;) {
        if (tid == 0)
            *sh_tile = (int)__hip_atomic_fetch_add(&ctrl[128], 8u, __ATOMIC_RELAXED,
                                                   __HIP_MEMORY_SCOPE_AGENT);
        __syncthreads();
        int start = *sh_tile;
        if (start >= 1024) return;
        for (int tt = start; tt < start + 8 && tt < 1024; ++tt) {
            int local = tt;
            const u16* Bt;
            u16* C;
            if (local < 512) { Bt = Bh; C = Ch; }
            else { Bt = Ba; C = Ca; local -= 512; }
            int m0 = (local >> 3) * 64, n0 = (local & 7) * 64;
            f32x4 acc[2][2] = {};
            int ar = tid >> 2, ac = (tid & 3) * 8;
            const u16* Ap = amem + (m0 + ar) * 512 + ac;
            const u16* Bp = Bt + (n0 + ar) * 512 + ac;
            for (int kt = 0; kt < 16; ++kt) {
                uint4 av = *(const uint4*)(Ap + kt * 32);
                uint4 bv = *(const uint4*)(Bp + kt * 32);
                __syncthreads();
                *(uint4*)&As[ar][ac] = av;
                *(uint4*)&Bs[ar][ac] = bv;
                __syncthreads();
                bf16x8 a0 = *(const bf16x8*)&As[wm * 32 + l15][quad * 8];
                bf16x8 a1 = *(const bf16x8*)&As[wm * 32 + 16 + l15][quad * 8];
                bf16x8 b0 = *(const bf16x8*)&Bs[wn * 32 + l15][quad * 8];
                bf16x8 b1 = *(const bf16x8*)&Bs[wn * 32 + 16 + l15][quad * 8];
                acc[0][0] = __builtin_amdgcn_mfma_f32_16x16x32_bf16(a0, b0, acc[0][0], 0, 0, 0);
                acc[0][1] = __builtin_amdgcn_mfma_f32_16x16x32_bf16(a0, b1, acc[0][1], 0, 0, 0);
                acc[1][0] = __builtin_amdgcn_mfma_f32_16x16x32_bf16(a1, b0, acc[1][0], 0, 0, 0);
                acc[1][1] = __builtin_amdgcn_mfma_f32_16x16x32_bf16(a1, b1, acc[1][1], 0, 0, 0);
            }
            for (int ai = 0; ai < 2; ++ai)
                for (int bi = 0; bi < 2; ++bi) {
                    int rr = m0 + wm * 32 + ai * 16 + quad * 4;
                    int cc = n0 + wn * 32 + bi * 16 + l15;
                    for (int r = 0; r < 4; ++r) C[(rr + r) * 512 + cc] = f2b(acc[ai][bi][r]);
                }
            __syncthreads();
        }
    }
}

// ---------------- LSTM mega kernel: 256 blocks, runtime role assignment ----
__launch_bounds__(256, 1)
__global__ void k_lstm6(const u16* __restrict__ whh_bf, const float* __restrict__ xw,
                        const float* __restrict__ init_h, const float* __restrict__ init_c,
                        const u16* __restrict__ wq_hop_T, float* __restrict__ qbuf,
                        char* __restrict__ hbuf, u32* __restrict__ flags,
                        u32* __restrict__ ctrl,
                        const u16* __restrict__ amem_bf,
                        const u16* __restrict__ WmT_hop, const u16* __restrict__ WmT_attn,
                        u16* __restrict__ hop_feat, u16* __restrict__ attn_feat) {
    __shared__ u16 sBw0[32][520];
    __shared__ u16 sBw1[32][520];
    __shared__ u16 sAh[32][520];
    __shared__ u16 sWq[16][520];
    __shared__ float sgl[32][66];
    __shared__ u16 sgb[32][16];
    __shared__ int sh_role, sh_slot, sh_tile;
    int tid = threadIdx.x;
    if (tid == 0) {
        u32 xcc = 0;
        asm volatile("s_getreg_b32 %0, hwreg(HW_REG_XCC_ID, 0, 32)" : "=s"(xcc));
        xcc &= 0xFFu;
        if (blockIdx.x == 0) st_agent(&ctrl[0], xcc | 0x100u);
        // bounded wait for target XCD publication
        u32 tgt = 0x1FFu;
        for (int it = 0; it < 200000; ++it) {
            u32 v = ld_agent(&ctrl[0]);
            if (v & 0x100u) { tgt = v & 0xFFu; break; }
            __builtin_amdgcn_s_sleep(1);
        }
        int slotL = 1000;
        if (xcc == tgt)
            slotL = (int)__hip_atomic_fetch_add(&ctrl[64], 1u, __ATOMIC_RELAXED,
                                                __HIP_MEMORY_SCOPE_AGENT);
        if (blockIdx.x == 0) {
            // bounded decision: local iff exactly ~NW claims (a real XCD has 32 CUs;
            // garbage XCC reads -> everyone matches -> overshoot -> agent fallback)
            u32 mode = 2;
            bool ok = false;
            for (int it = 0; it < 60000; ++it) {
                if (ld_agent(&ctrl[64]) >= (u32)NW) { ok = true; break; }
                __builtin_amdgcn_s_sleep(4);
            }
            if (ok) {
                for (int it = 0; it < 3000; ++it) __builtin_amdgcn_s_sleep(2);  // settle
                if (ld_agent(&ctrl[64]) <= (u32)(NW + 8)) mode = 1;
            }
            st_agent(&ctrl[32], mode | 0x100u);
        }
        u32 mv;
        do {
            mv = ld_agent(&ctrl[32]);  // terminates: block 0 path above is bounded
        } while (!(mv & 0x100u));
        mv &= 0xFFu;
        int role = 0, slot = 0;
        if (mv == 1) {
            if (slotL < NW) { role = 1; slot = slotL; }
        } else {
            int sA = (int)__hip_atomic_fetch_add(&ctrl[96], 1u, __ATOMIC_RELAXED,
                                                 __HIP_MEMORY_SCOPE_AGENT);
            if (sA < NW) { role = 2; slot = sA; }
        }
        sh_role = role;
        sh_slot = slot;
    }
    __syncthreads();
    int role = sh_role, slot = sh_slot;
    if (role == 1)
        lstm_worker<true>(slot, sBw0, sBw1, sAh, sWq, sgl, sgb,
                          whh_bf, xw, init_h, init_c, wq_hop_T, qbuf, hbuf, flags);
    else if (role == 2)
        lstm_worker<false>(slot, sBw0, sBw1, sAh, sWq, sgl, sgb,
                           whh_bf, xw, init_h, init_c, wq_hop_T, qbuf, hbuf, flags);
    else
        feat_worker((u16(*)[40])&sBw0[0][0], (u16(*)[40])&sBw1[0][0], ctrl,
                    amem_bf, WmT_hop, WmT_attn, hop_feat, attn_feat, &sh_tile);
}

// ---------------- fused hop attention --------------------------------------
__launch_bounds__(256)
__global__ void k_hop(const u16* __restrict__ feat, const float* __restrict__ q,
                      const float* __restrict__ v, const int* __restrict__ mem_sizes,
                      u16* __restrict__ nq) {
    __shared__ float qs[512];
    __shared__ float vs[512];
    __shared__ float sc[128];
    __shared__ float ns[128];
    int bt = blockIdx.x;
    int b = bt >> 5;
    int tid = threadIdx.x;
    qs[tid] = q[bt * 512 + tid];
    qs[tid + 256] = q[bt * 512 + 256 + tid];
    vs[tid] = v[tid];
    vs[tid + 256] = v[tid + 256];
    __syncthreads();
    int lane = tid & 63, w = tid >> 6;
    int h0 = lane * 8;
    float qv[8], vv[8];
#pragma unroll
    for (int i = 0; i < 8; ++i) { qv[i] = qs[h0 + i]; vv[i] = vs[h0 + i]; }
    const u16* fb = feat + (size_t)b * 128 * 512;
    for (int i = 0; i < 32; ++i) {
        int n = w * 32 + i;
        uint4 fv = *(const uint4*)(fb + n * 512 + h0);
        float fr[8];
        fr[0] = b2f((u16)(fv.x & 0xFFFF)); fr[1] = b2f((u16)(fv.x >> 16));
        fr[2] = b2f((u16)(fv.y & 0xFFFF)); fr[3] = b2f((u16)(fv.y >> 16));
        fr[4] = b2f((u16)(fv.z & 0xFFFF)); fr[5] = b2f((u16)(fv.z >> 16));
        fr[6] = b2f((u16)(fv.w & 0xFFFF)); fr[7] = b2f((u16)(fv.w >> 16));
        float a = 0.f;
#pragma unroll
        for (int jj = 0; jj < 8; ++jj) a += fast_tanh(fr[jj] + qv[jj]) * vv[jj];
        for (int off = 1; off < 64; off <<= 1) a += __shfl_xor(a, off);
        if (lane == 0) sc[n] = a;
    }
    __syncthreads();
    if (tid < 64) {
        int ms = mem_sizes[b];
        float s0 = (tid < ms) ? sc[tid] : -1e30f;
        float s1 = (tid + 64 < ms) ? sc[tid + 64] : -1e30f;
        float m = fmaxf(s0, s1);
        for (int off = 1; off < 64; off <<= 1) m = fmaxf(m, __shfl_xor(m, off));
        float e0 = __expf(s0 - m), e1 = __expf(s1 - m);
        float s = e0 + e1;
        for (int off = 1; off < 64; off <<= 1) s += __shfl_xor(s, off);
        float r = fast_rcp(s);
        ns[tid] = e0 * r;
        ns[tid + 64] = e1 * r;
    }
    __syncthreads();
    float a0 = 0.f, a1 = 0.f;
    int hc = tid * 2;
    for (int n = 0; n < 128; ++n) {
        float f = ns[n];
        unsigned int pv = *(const unsigned int*)(fb + n * 512 + hc);
        a0 += f * b2f((u16)(pv & 0xFFFF));
        a1 += f * b2f((u16)(pv >> 16));
    }
    ((unsigned int*)nq)[bt * 256 + tid] = pack2(a0, a1);
}

// ---------------- final scores -> out (f32) --------------------------------
__launch_bounds__(256)
__global__ void k_score(const u16* __restrict__ feat, const float* __restrict__ q,
                        const float* __restrict__ v, float* __restrict__ outp) {
    __shared__ float qs[512];
    __shared__ float vs[512];
    __shared__ float sc[128];
    int bt = blockIdx.x;
    int b = bt >> 5;
    int tid = threadIdx.x;
    qs[tid] = q[bt * 512 + tid];
    qs[tid + 256] = q[bt * 512 + 256 + tid];
    vs[tid] = v[tid];
    vs[tid + 256] = v[tid + 256];
    __syncthreads();
    int lane = tid & 63, w = tid >> 6;
    int h0 = lane * 8;
    float qv[8], vv[8];
#pragma unroll
    for (int i = 0; i < 8; ++i) { qv[i] = qs[h0 + i]; vv[i] = vs[h0 + i]; }
    const u16* fb = feat + (size_t)b * 128 * 512;
    for (int i = 0; i < 32; ++i) {
        int n = w * 32 + i;
        uint4 fv = *(const uint4*)(fb + n * 512 + h0);
        float fr[8];
        fr[0] = b2f((u16)(fv.x & 0xFFFF)); fr[1] = b2f((u16)(fv.x >> 16));
        fr[2] = b2f((u16)(fv.y & 0xFFFF)); fr[3] = b2f((u16)(fv.y >> 16));
        fr[4] = b2f((u16)(fv.z & 0xFFFF)); fr[5] = b2f((u16)(fv.z >> 16));
        fr[6] = b2f((u16)(fv.w & 0xFFFF)); fr[7] = b2f((u16)(fv.w >> 16));
        float a = 0.f;
#pragma unroll
        for (int jj = 0; jj < 8; ++jj) a += fast_tanh(fr[jj] + qv[jj]) * vv[jj];
        for (int off = 1; off < 64; off <<= 1) a += __shfl_xor(a, off);
        if (lane == 0) sc[n] = a;
    }
    __syncthreads();
    if (tid < 128) outp[bt * 128 + tid] = sc[tid];
}

extern "C" void kernel_launch(void* const* d_in, const int* in_sizes, int n_in,
                              void* d_out, int out_size, void* d_ws, size_t ws_size,
                              hipStream_t stream) {
    (void)in_sizes; (void)n_in; (void)out_size; (void)ws_size;
    const float* attn_mem = (const float*)d_in[0];
    const int* mem_sizes = (const int*)d_in[1];
    const float* lstm_in = (const float*)d_in[2];
    const float* init_h = (const float*)d_in[3];
    const float* init_c = (const float*)d_in[4];
    const float* init_i = (const float*)d_in[5];
    const float* w_ih = (const float*)d_in[6];
    const float* w_hh = (const float*)d_in[7];
    const float* b_ih = (const float*)d_in[8];
    const float* b_hh = (const float*)d_in[9];
    const float* attn_wm = (const float*)d_in[10];
    const float* attn_wq = (const float*)d_in[11];
    const float* attn_v = (const float*)d_in[12];
    const float* hop_wm = (const float*)d_in[13];
    const float* hop_wq = (const float*)d_in[14];
    const float* hop_v = (const float*)d_in[15];
    float* out = (float*)d_out;

    char* ws = (char*)d_ws;
    size_t off = 0;
    auto alloc = [&](size_t bytes) {
        void* p = ws + off;
        off += (bytes + 255) & ~(size_t)255;
        return p;
    };
    u16* amem_bf = (u16*)alloc(4096 * 512 * 2);
    u16* xfull_bf = (u16*)alloc(1024 * 512 * 2);
    u16* wih_bf = (u16*)alloc(2048 * 512 * 2);
    u16* whh_bf = (u16*)alloc(2048 * 512 * 2);
    u16* WmT_hop = (u16*)alloc(512 * 512 * 2);
    u16* WmT_attn = (u16*)alloc(512 * 512 * 2);
    u16* WqT_hop = (u16*)alloc(512 * 512 * 2);
    u16* WqT_attn = (u16*)alloc(512 * 512 * 2);
    float* xw = (float*)alloc(1024 * 2048 * 4);
    u16* hop_feat = (u16*)alloc(4096 * 512 * 2);
    u16* attn_feat = (u16*)alloc(4096 * 512 * 2);
    char* hbuf = (char*)alloc(2 * NW * 1024);
    u32* flags = (u32*)alloc(NW * FLAG_STRIDE * 4);
    u32* ctrl = (u32*)alloc(1024);
    float* qbuf = (float*)alloc(1024 * 512 * 4);
    u16* nq = (u16*)alloc(1024 * 512 * 2);

    k_prep<<<5632, 256, 0, stream>>>(attn_mem, amem_bf, w_ih, wih_bf, w_hh, whh_bf,
                                     lstm_in, init_i, xfull_bf,
                                     attn_wm, hop_wm, hop_wq, attn_wq,
                                     WmT_attn, WmT_hop, WqT_hop, WqT_attn, flags, ctrl);
    k_xw<<<512, 256, 0, stream>>>(xfull_bf, wih_bf, xw, b_ih, b_hh);
    k_lstm6<<<256, 256, 0, stream>>>(whh_bf, xw, init_h, init_c, WqT_hop, qbuf,
                                     hbuf, flags, ctrl,
                                     amem_bf, WmT_hop, WmT_attn, hop_feat, attn_feat);
    k_hop<<<1024, 256, 0, stream>>>(hop_feat, qbuf, hop_v, mem_sizes, nq);
    k_gemm<<<dim3(8, 16), 256, 0, stream>>>(nq, WqT_attn, qbuf, 512);
    k_score<<<1024, 256, 0, stream>>>(attn_feat, qbuf, attn_v, out);
}

// Round 13
// 273.610 us; speedup vs baseline: 1.5642x; 1.5642x over previous
//
#include <hip/hip_runtime.h>

typedef unsigned short u16;
typedef unsigned int u32;
typedef unsigned long long u64;
typedef __bf16 bf16x8 __attribute__((ext_vector_type(8)));
typedef float f32x4 __attribute__((ext_vector_type(4)));
typedef int i32x4 __attribute__((ext_vector_type(4)));

__device__ __forceinline__ float b2f(u16 u) {
    unsigned int x = ((unsigned int)u) << 16;
    return __builtin_bit_cast(float, x);
}
__device__ __forceinline__ u16 f2b(float f) {
    unsigned int u = __builtin_bit_cast(unsigned int, f);
    unsigned int r = (u + 0x7FFFu + ((u >> 16) & 1u)) >> 16;
    return (u16)r;
}
__device__ __forceinline__ unsigned int pack2(float a, float b) {
    return (unsigned int)f2b(a) | ((unsigned int)f2b(b) << 16);
}
__device__ __forceinline__ float fast_rcp(float x) { return __builtin_amdgcn_rcpf(x); }
__device__ __forceinline__ float fast_tanh(float x) {
    float e = __expf(2.f * x);
    return 1.f - 2.f * fast_rcp(e + 1.f);
}
__device__ __forceinline__ float fast_sig(float x) {
    float e = __expf(-x);
    return fast_rcp(1.f + e);
}

#define FLAG_STRIDE 32
#define NW 32  // LSTM workers, 16 k-cols each

__device__ __forceinline__ u32 ld_agent(const u32* p) {
    return __hip_atomic_load(p, __ATOMIC_RELAXED, __HIP_MEMORY_SCOPE_AGENT);
}
__device__ __forceinline__ void st_agent(u32* p, u32 v) {
    __hip_atomic_store(p, v, __ATOMIC_RELAXED, __HIP_MEMORY_SCOPE_AGENT);
}
// XCD-local (same-L2) data ops: sc0 = bypass L1 (CDNA L1 is write-through)
__device__ __forceinline__ void st16_sc0(void* p, i32x4 v) {
    asm volatile("global_store_dwordx4 %0, %1, off sc0" :: "v"(p), "v"(v) : "memory");
}
__device__ __forceinline__ i32x4 ld16_sc0(const void* p) {
    i32x4 v;
    asm volatile("global_load_dwordx4 %0, %1, off sc0" : "=v"(v) : "v"(p) : "memory");
    return v;
}
__device__ __forceinline__ void waitvm0_dep8(i32x4* v) {
    asm volatile("s_waitcnt vmcnt(0)"
                 : "+v"(v[0]), "+v"(v[1]), "+v"(v[2]), "+v"(v[3]),
                   "+v"(v[4]), "+v"(v[5]), "+v"(v[6]), "+v"(v[7]));
}

// ---------------- fused prep: casts + xfull + 4x transpose + ctrl zero ------
__launch_bounds__(256)
__global__ void k_prep(const float* __restrict__ attn_mem, u16* __restrict__ amem_bf,
                       const float* __restrict__ w_ih, u16* __restrict__ wih_bf,
                       const float* __restrict__ w_hh, u16* __restrict__ whh_bf,
                       const float* __restrict__ lstm_in, const float* __restrict__ init_i,
                       u16* __restrict__ xfull,
                       const float* s0, const float* s1, const float* s2, const float* s3,
                       u16* d0, u16* d1, u16* d2, u16* d3,
                       u32* __restrict__ flags, u32* __restrict__ ctrl) {
    __shared__ float tile[32][33];
    int bid = blockIdx.x;
    int tid = threadIdx.x;
    if (bid == 0) {
        if (tid < NW) st_agent(&flags[tid * FLAG_STRIDE], 0u);
        if (tid >= 64 && tid < 72) st_agent(&ctrl[(tid - 64) * 32], 0u);
    }
    if (bid < 4096) {
        const float* s;
        u16* d;
        int i;
        if (bid < 2048) { s = attn_mem; d = amem_bf; i = bid * 256 + tid; }
        else if (bid < 3072) { s = w_ih; d = wih_bf; i = (bid - 2048) * 256 + tid; }
        else { s = w_hh; d = whh_bf; i = (bid - 3072) * 256 + tid; }
        float4 a = ((const float4*)s)[i];
        uint2 p;
        p.x = pack2(a.x, a.y);
        p.y = pack2(a.z, a.w);
        ((uint2*)d)[i] = p;
    } else if (bid < 4608) {
        int idx = (bid - 4096) * 256 + tid;
        int c = idx & 127;
        int t = (idx >> 7) & 31;
        int b = idx >> 12;
        const float4* src = (t == 0) ? ((const float4*)init_i) + c
                                     : ((const float4*)lstm_in) + ((b * 31 + (t - 1)) * 128 + c);
        float4 a = *src;
        uint2 p;
        p.x = pack2(a.x, a.y);
        p.y = pack2(a.z, a.w);
        ((uint2*)xfull)[idx] = p;
    } else {
        int local = bid - 4608;
        int z = local >> 8, rem = local & 255;
        int by = (rem >> 4) * 32, bx = (rem & 15) * 32;
        const float* s;
        u16* d;
        switch (z) {
            case 0: s = s0; d = d0; break;
            case 1: s = s1; d = d1; break;
            case 2: s = s2; d = d2; break;
            default: s = s3; d = d3; break;
        }
        int tx = tid & 31, ty = tid >> 5;
        for (int i = 0; i < 32; i += 8) tile[ty + i][tx] = s[(by + ty + i) * 512 + bx + tx];
        __syncthreads();
        for (int i = 0; i < 32; i += 8) d[(bx + ty + i) * 512 + by + tx] = f2b(tile[tx][ty + i]);
    }
}

// ---------------- xw GEMM: 512 blocks --------------------------------------
__launch_bounds__(256)
__global__ void k_xw(const u16* __restrict__ xfull, const u16* __restrict__ wih,
                     float* __restrict__ xw,
                     const float* __restrict__ b_ih, const float* __restrict__ b_hh) {
    __shared__ u16 As[64][40];
    __shared__ u16 Bs[64][40];
    int id = blockIdx.x;
    int m0 = (id >> 5) * 64, n0 = (id & 31) * 64;
    int tid = threadIdx.x;
    int lane = tid & 63, w = tid >> 6;
    int wm = w >> 1, wn = w & 1;
    int l15 = lane & 15, quad = lane >> 4;
    f32x4 acc[2][2] = {};
    int ar = tid >> 2, ac = (tid & 3) * 8;
    const u16* Ap = xfull + (m0 + ar) * 512 + ac;
    const u16* Bp = wih + (n0 + ar) * 512 + ac;
    for (int kt = 0; kt < 16; ++kt) {
        uint4 av = *(const uint4*)(Ap + kt * 32);
        uint4 bv = *(const uint4*)(Bp + kt * 32);
        __syncthreads();
        *(uint4*)&As[ar][ac] = av;
        *(uint4*)&Bs[ar][ac] = bv;
        __syncthreads();
        bf16x8 a0 = *(const bf16x8*)&As[wm * 32 + l15][quad * 8];
        bf16x8 a1 = *(const bf16x8*)&As[wm * 32 + 16 + l15][quad * 8];
        bf16x8 b0 = *(const bf16x8*)&Bs[wn * 32 + l15][quad * 8];
        bf16x8 b1 = *(const bf16x8*)&Bs[wn * 32 + 16 + l15][quad * 8];
        acc[0][0] = __builtin_amdgcn_mfma_f32_16x16x32_bf16(a0, b0, acc[0][0], 0, 0, 0);
        acc[0][1] = __builtin_amdgcn_mfma_f32_16x16x32_bf16(a0, b1, acc[0][1], 0, 0, 0);
        acc[1][0] = __builtin_amdgcn_mfma_f32_16x16x32_bf16(a1, b0, acc[1][0], 0, 0, 0);
        acc[1][1] = __builtin_amdgcn_mfma_f32_16x16x32_bf16(a1, b1, acc[1][1], 0, 0, 0);
    }
    for (int ai = 0; ai < 2; ++ai)
        for (int bi = 0; bi < 2; ++bi) {
            int row = m0 + wm * 32 + ai * 16 + quad * 4;
            int col = n0 + wn * 32 + bi * 16 + l15;
            float bias = b_ih[col] + b_hh[col];
            for (int r = 0; r < 4; ++r) xw[(row + r) * 2048 + col] = acc[ai][bi][r] + bias;
        }
}

// ---------------- standalone GEMM for nq @ WqT_attn ------------------------
__launch_bounds__(256)
__global__ void k_gemm(const u16* __restrict__ A, const u16* __restrict__ Bt,
                       float* __restrict__ C, int GN) {
    __shared__ u16 As[64][40];
    __shared__ u16 Bs[64][40];
    int m0 = blockIdx.y * 64, n0 = blockIdx.x * 64;
    int tid = threadIdx.x;
    int lane = tid & 63, w = tid >> 6;
    int wm = w >> 1, wn = w & 1;
    int l15 = lane & 15, quad = lane >> 4;
    f32x4 acc[2][2] = {};
    int ar = tid >> 2, ac = (tid & 3) * 8;
    const u16* Ap = A + (m0 + ar) * 512 + ac;
    const u16* Bp = Bt + (n0 + ar) * 512 + ac;
    for (int kt = 0; kt < 16; ++kt) {
        uint4 av = *(const uint4*)(Ap + kt * 32);
        uint4 bv = *(const uint4*)(Bp + kt * 32);
        __syncthreads();
        *(uint4*)&As[ar][ac] = av;
        *(uint4*)&Bs[ar][ac] = bv;
        __syncthreads();
        bf16x8 a0 = *(const bf16x8*)&As[wm * 32 + l15][quad * 8];
        bf16x8 a1 = *(const bf16x8*)&As[wm * 32 + 16 + l15][quad * 8];
        bf16x8 b0 = *(const bf16x8*)&Bs[wn * 32 + l15][quad * 8];
        bf16x8 b1 = *(const bf16x8*)&Bs[wn * 32 + 16 + l15][quad * 8];
        acc[0][0] = __builtin_amdgcn_mfma_f32_16x16x32_bf16(a0, b0, acc[0][0], 0, 0, 0);
        acc[0][1] = __builtin_amdgcn_mfma_f32_16x16x32_bf16(a0, b1, acc[0][1], 0, 0, 0);
        acc[1][0] = __builtin_amdgcn_mfma_f32_16x16x32_bf16(a1, b0, acc[1][0], 0, 0, 0);
        acc[1][1] = __builtin_amdgcn_mfma_f32_16x16x32_bf16(a1, b1, acc[1][1], 0, 0, 0);
    }
    for (int ai = 0; ai < 2; ++ai)
        for (int bi = 0; bi < 2; ++bi) {
            int row = m0 + wm * 32 + ai * 16 + quad * 4;
            int col = n0 + wn * 32 + bi * 16 + l15;
            for (int r = 0; r < 4; ++r) C[(row + r) * GN + col] = acc[ai][bi][r];
        }
}

// ---------------- LSTM worker: 16 k-cols, data path templated --------------
// Flags ALWAYS agent-scope (hang-proof); LOCAL switches only the h data path.
template <bool LOCAL>
__device__ __forceinline__ void lstm_worker(int slot,
        u16 (*Bw0)[520], u16 (*Bw1)[520], u16 (*Ah)[520], u16 (*Wq)[520],
        float (*gl)[66], u16 (*gb)[16],
        const u16* __restrict__ whh, const float* __restrict__ xw,
        const float* __restrict__ init_h, const float* __restrict__ init_c,
        const u16* __restrict__ wqT, float* __restrict__ qbuf,
        char* __restrict__ hbuf, u32* __restrict__ flags) {
    int tid = threadIdx.x;
    int lane = tid & 63, w = tid >> 6;
    int l15 = lane & 15, quad = lane >> 4;
    int k0 = slot * 16;
    // stage w_hh slice: virtual col c=gate*16+kl <-> w_hh row gate*512+k0+kl
    {
        int r = tid >> 2, s4 = tid & 3;
        u16 (*BwT)[520] = (r < 32) ? Bw0 : Bw1;
        int rr = r & 31;
        int j = (r >> 4) * 512 + k0 + (r & 15);
        const uint4* src = (const uint4*)(whh + j * 512);
        for (int i = 0; i < 16; ++i)
            *(uint4*)&BwT[rr][(s4 * 16 + i) * 8] = src[s4 * 16 + i];
    }
    // stage Wq (16 rows = q2 output cols k0..k0+15)
    {
        int r = tid >> 4, s16 = tid & 15;
        const uint4* src = (const uint4*)(wqT + (k0 + r) * 512);
        for (int i = 0; i < 4; ++i)
            *(uint4*)&Wq[r][(s16 + 16 * i) * 8] = src[s16 + 16 * i];
    }
    int row = tid >> 3, seg = tid & 7;
    for (int i = 0; i < 8; ++i) {
        int col = (seg + 8 * i) * 8;
        float4 f0 = *(const float4*)(init_h + col);
        float4 f1 = *(const float4*)(init_h + col + 4);
        uint4 p;
        p.x = pack2(f0.x, f0.y);
        p.y = pack2(f0.z, f0.w);
        p.z = pack2(f1.x, f1.y);
        p.w = pack2(f1.z, f1.w);
        *(uint4*)&Ah[row][col] = p;
    }
    int kl0 = seg * 2;
    float c0 = init_c[k0 + kl0], c1 = init_c[k0 + kl0 + 1];
    float2 xc[4];
    {
        const float* p = xw + (row << 5) * 2048 + k0 + kl0;
        for (int g = 0; g < 4; ++g) xc[g] = *(const float2*)(p + g * 512);
    }
    int mw = w >> 1, ni = w & 1;
    u16 (*BwH)[520] = ni ? Bw1 : Bw0;
    __syncthreads();
    for (int t = 0; t < 32; ++t) {
        f32x4 acc0 = {}, acc1 = {};
#pragma unroll
        for (int kc = 0; kc < 16; ++kc) {
            bf16x8 af = *(const bf16x8*)&Ah[mw * 16 + l15][kc * 32 + quad * 8];
            bf16x8 bf0 = *(const bf16x8*)&BwH[l15][kc * 32 + quad * 8];
            bf16x8 bf1 = *(const bf16x8*)&BwH[16 + l15][kc * 32 + quad * 8];
            acc0 = __builtin_amdgcn_mfma_f32_16x16x32_bf16(af, bf0, acc0, 0, 0, 0);
            acc1 = __builtin_amdgcn_mfma_f32_16x16x32_bf16(af, bf1, acc1, 0, 0, 0);
        }
        {
            int r0 = mw * 16 + quad * 4;
            for (int r = 0; r < 4; ++r) {
                gl[r0 + r][ni * 32 + l15] = acc0[r];
                gl[r0 + r][ni * 32 + 16 + l15] = acc1[r];
            }
        }
        __syncthreads();  // #1
        {
            float gi = gl[row][kl0] + xc[0].x;
            float gf = gl[row][16 + kl0] + xc[1].x;
            float gg = gl[row][32 + kl0] + xc[2].x;
            float go = gl[row][48 + kl0] + xc[3].x;
            float cn = fast_sig(gf) * c0 + fast_sig(gi) * fast_tanh(gg);
            c0 = cn;
            gb[row][kl0] = f2b(fast_sig(go) * fast_tanh(cn));
            gi = gl[row][kl0 + 1] + xc[0].y;
            gf = gl[row][16 + kl0 + 1] + xc[1].y;
            gg = gl[row][32 + kl0 + 1] + xc[2].y;
            go = gl[row][48 + kl0 + 1] + xc[3].y;
            cn = fast_sig(gf) * c1 + fast_sig(gi) * fast_tanh(gg);
            c1 = cn;
            gb[row][kl0 + 1] = f2b(fast_sig(go) * fast_tanh(cn));
        }
        __syncthreads();  // #2
        char* hb_base = hbuf + (t & 1) * (NW * 1024);
        if (tid < 64) {
            int b2 = tid >> 1, half = tid & 1;
            char* dst = hb_base + slot * 1024 + b2 * 32 + half * 16;
            if (LOCAL) {
                st16_sc0(dst, *(const i32x4*)&gb[b2][half * 8]);
            } else {
                const u64* sv = (const u64*)&gb[b2][half * 8];
                u64* d64 = (u64*)dst;
                __hip_atomic_store(&d64[0], sv[0], __ATOMIC_RELAXED, __HIP_MEMORY_SCOPE_AGENT);
                __hip_atomic_store(&d64[1], sv[1], __ATOMIC_RELAXED, __HIP_MEMORY_SCOPE_AGENT);
            }
            __builtin_amdgcn_s_waitcnt(0);  // h stores acked before flag store
            if (tid == 0) st_agent(&flags[slot * FLAG_STRIDE], (u32)(t + 1));
            for (;;) {
                u32 f = 0xFFFFFFFFu;
                if (tid < NW) f = ld_agent(&flags[tid * FLAG_STRIDE]);
                if (__ballot(f > (u32)t) == ~0ull) break;
                __builtin_amdgcn_s_sleep(1);
            }
        } else if (t > 0 && w <= 2) {
            // q2 slice for time t-1 (Ah = h(t) = query[t-1]) on waves 1-2
            f32x4 a2 = {};
#pragma unroll
            for (int kc = 0; kc < 16; ++kc) {
                bf16x8 af = *(const bf16x8*)&Ah[(w - 1) * 16 + l15][kc * 32 + quad * 8];
                bf16x8 bq = *(const bf16x8*)&Wq[l15][kc * 32 + quad * 8];
                a2 = __builtin_amdgcn_mfma_f32_16x16x32_bf16(af, bq, a2, 0, 0, 0);
            }
            int bb = (w - 1) * 16 + quad * 4;
            for (int r = 0; r < 4; ++r)
                qbuf[(((bb + r) << 5) + (t - 1)) * 512 + k0 + l15] = a2[r];
        }
        __syncthreads();  // #3
        int tn = (t < 31) ? t + 1 : 31;
        float2 xn[4];
        {
            const float* p = xw + ((row << 5) + tn) * 2048 + k0 + kl0;
            for (int g = 0; g < 4; ++g) xn[g] = *(const float2*)(p + g * 512);
        }
        if (LOCAL) {
            i32x4 v[8];
#pragma unroll
            for (int i = 0; i < 8; ++i) {
                int idx = seg + 8 * i;
                v[i] = ld16_sc0(hb_base + (idx >> 1) * 1024 + row * 32 + (idx & 1) * 16);
            }
            waitvm0_dep8(v);  // dependency-tied vmcnt(0): no reorder hazard
#pragma unroll
            for (int i = 0; i < 8; ++i) {
                int idx = seg + 8 * i;
                *(i32x4*)&Ah[row][(idx >> 1) * 16 + (idx & 1) * 8] = v[i];
            }
        } else {
#pragma unroll
            for (int i = 0; i < 8; ++i) {
                int idx = seg + 8 * i;
                u64* sp = (u64*)(hb_base + (idx >> 1) * 1024 + row * 32 + (idx & 1) * 16);
                u64 v0 = __hip_atomic_load(&sp[0], __ATOMIC_RELAXED, __HIP_MEMORY_SCOPE_AGENT);
                u64 v1 = __hip_atomic_load(&sp[1], __ATOMIC_RELAXED, __HIP_MEMORY_SCOPE_AGENT);
                u64* d = (u64*)&Ah[row][(idx >> 1) * 16 + (idx & 1) * 8];
                d[0] = v0;
                d[1] = v1;
            }
        }
        __syncthreads();  // #4
        for (int g = 0; g < 4; ++g) xc[g] = xn[g];
    }
    // epilogue: q2 for t=31 (Ah = h(32) = query[31])
    if (w == 1 || w == 2) {
        f32x4 a2 = {};
#pragma unroll
        for (int kc = 0; kc < 16; ++kc) {
            bf16x8 af = *(const bf16x8*)&Ah[(w - 1) * 16 + l15][kc * 32 + quad * 8];
            bf16x8 bq = *(const bf16x8*)&Wq[l15][kc * 32 + quad * 8];
            a2 = __builtin_amdgcn_mfma_f32_16x16x32_bf16(af, bq, a2, 0, 0, 0);
        }
        int bb = (w - 1) * 16 + quad * 4;
        for (int r = 0; r < 4; ++r)
            qbuf[(((bb + r) << 5) + 31) * 512 + k0 + l15] = a2[r];
    }
}

// ---------------- feat worker: pulls 8-tile batches from queue -------------
__device__ __forceinline__ void feat_worker(u16 (*As)[40], u16 (*Bs)[40],
        u32* __restrict__ ctrl, const u16* __restrict__ amem,
        const u16* __restrict__ Bh, const u16* __restrict__ Ba,
        u16* __restrict__ Ch, u16* __restrict__ Ca, int* sh_tile) {
    int tid = threadIdx.x;
    int lane = tid & 63, w = tid >> 6;
    int wm = w >> 1, wn = w & 1;
    int l15 = lane & 15, quad = lane >> 4;
    for (;;) {
        if (tid == 0)
            *sh_tile = (int)__hip_atomic_fetch_add(&ctrl[128], 8u, __ATOMIC_RELAXED,
                                                   __HIP_MEMORY_SCOPE_AGENT);
        __syncthreads();
        int start = *sh_tile;
        if (start >= 1024) return;
        for (int tt = start; tt < start + 8 && tt < 1024; ++tt) {
            int local = tt;
            const u16* Bt;
            u16* C;
            if (local < 512) { Bt = Bh; C = Ch; }
            else { Bt = Ba; C = Ca; local -= 512; }
            int m0 = (local >> 3) * 64, n0 = (local & 7) * 64;
            f32x4 acc[2][2] = {};
            int ar = tid >> 2, ac = (tid & 3) * 8;
            const u16* Ap = amem + (m0 + ar) * 512 + ac;
            const u16* Bp = Bt + (n0 + ar) * 512 + ac;
            for (int kt = 0; kt < 16; ++kt) {
                uint4 av = *(const uint4*)(Ap + kt * 32);
                uint4 bv = *(const uint4*)(Bp + kt * 32);
                __syncthreads();
                *(uint4*)&As[ar][ac] = av;
                *(uint4*)&Bs[ar][ac] = bv;
                __syncthreads();
                bf16x8 a0 = *(const bf16x8*)&As[wm * 32 + l15][quad * 8];
                bf16x8 a1 = *(const bf16x8*)&As[wm * 32 + 16 + l15][quad * 8];
                bf16x8 b0 = *(const bf16x8*)&Bs[wn * 32 + l15][quad * 8];
                bf16x8 b1 = *(const bf16x8*)&Bs[wn * 32 + 16 + l15][quad * 8];
                acc[0][0] = __builtin_amdgcn_mfma_f32_16x16x32_bf16(a0, b0, acc[0][0], 0, 0, 0);
                acc[0][1] = __builtin_amdgcn_mfma_f32_16x16x32_bf16(a0, b1, acc[0][1], 0, 0, 0);
                acc[1][0] = __builtin_amdgcn_mfma_f32_16x16x32_bf16(a1, b0, acc[1][0], 0, 0, 0);
                acc[1][1] = __builtin_amdgcn_mfma_f32_16x16x32_bf16(a1, b1, acc[1][1], 0, 0, 0);
            }
            for (int ai = 0; ai < 2; ++ai)
                for (int bi = 0; bi < 2; ++bi) {
                    int rr = m0 + wm * 32 + ai * 16 + quad * 4;
                    int cc = n0 + wn * 32 + bi * 16 + l15;
                    for (int r = 0; r < 4; ++r) C[(rr + r) * 512 + cc] = f2b(acc[ai][bi][r]);
                }
            __syncthreads();
        }
    }
}

// ---------------- LSTM mega kernel: 256 blocks, runtime role assignment ----
__launch_bounds__(256, 1)
__global__ void k_lstm6(const u16* __restrict__ whh_bf, const float* __restrict__ xw,
                        const float* __restrict__ init_h, const float* __restrict__ init_c,
                        const u16* __restrict__ wq_hop_T, float* __restrict__ qbuf,
                        char* __restrict__ hbuf, u32* __restrict__ flags,
                        u32* __restrict__ ctrl,
                        const u16* __restrict__ amem_bf,
                        const u16* __restrict__ WmT_hop, const u16* __restrict__ WmT_attn,
                        u16* __restrict__ hop_feat, u16* __restrict__ attn_feat) {
    __shared__ u16 sBw0[32][520];
    __shared__ u16 sBw1[32][520];
    __shared__ u16 sAh[32][520];
    __shared__ u16 sWq[16][520];
    __shared__ float sgl[32][66];
    __shared__ u16 sgb[32][16];
    __shared__ int sh_role, sh_slot, sh_tile;
    int tid = threadIdx.x;
    if (tid == 0) {
        u32 xcc = 0;
        asm volatile("s_getreg_b32 %0, hwreg(HW_REG_XCC_ID, 0, 32)" : "=s"(xcc));
        xcc &= 0xFFu;
        if (blockIdx.x == 0) st_agent(&ctrl[0], xcc | 0x100u);
        // bounded wait for target XCD publication
        u32 tgt = 0x1FFu;
        for (int it = 0; it < 200000; ++it) {
            u32 v = ld_agent(&ctrl[0]);
            if (v & 0x100u) { tgt = v & 0xFFu; break; }
            __builtin_amdgcn_s_sleep(1);
        }
        int slotL = 1000;
        if (xcc == tgt)
            slotL = (int)__hip_atomic_fetch_add(&ctrl[64], 1u, __ATOMIC_RELAXED,
                                                __HIP_MEMORY_SCOPE_AGENT);
        if (blockIdx.x == 0) {
            // bounded decision, SHORT settle (r12's 3000x sleep(2) ~= 175us was
            // the regression; claims saturate in ~2us, garbage-XCC overshoots
            // equally fast). ~6us window total.
            u32 mode = 2;
            bool ok = false;
            for (int it = 0; it < 60000; ++it) {
                if (ld_agent(&ctrl[64]) >= (u32)NW) { ok = true; break; }
                __builtin_amdgcn_s_sleep(1);
            }
            if (ok) {
                for (int it = 0; it < 100; ++it) __builtin_amdgcn_s_sleep(2);  // ~6us settle
                if (ld_agent(&ctrl[64]) <= (u32)(NW + 8)) mode = 1;
            }
            st_agent(&ctrl[32], mode | 0x100u);
        }
        u32 mv;
        do {
            mv = ld_agent(&ctrl[32]);  // terminates: block 0 path above is bounded
        } while (!(mv & 0x100u));
        mv &= 0xFFu;
        int role = 0, slot = 0;
        if (mv == 1) {
            if (slotL < NW) { role = 1; slot = slotL; }
        } else {
            int sA = (int)__hip_atomic_fetch_add(&ctrl[96], 1u, __ATOMIC_RELAXED,
                                                 __HIP_MEMORY_SCOPE_AGENT);
            if (sA < NW) { role = 2; slot = sA; }
        }
        sh_role = role;
        sh_slot = slot;
    }
    __syncthreads();
    int role = sh_role, slot = sh_slot;
    if (role == 1)
        lstm_worker<true>(slot, sBw0, sBw1, sAh, sWq, sgl, sgb,
                          whh_bf, xw, init_h, init_c, wq_hop_T, qbuf, hbuf, flags);
    else if (role == 2)
        lstm_worker<false>(slot, sBw0, sBw1, sAh, sWq, sgl, sgb,
                           whh_bf, xw, init_h, init_c, wq_hop_T, qbuf, hbuf, flags);
    else
        feat_worker((u16(*)[40])&sBw0[0][0], (u16(*)[40])&sBw1[0][0], ctrl,
                    amem_bf, WmT_hop, WmT_attn, hop_feat, attn_feat, &sh_tile);
}

// ---------------- fused hop attention --------------------------------------
__launch_bounds__(256)
__global__ void k_hop(const u16* __restrict__ feat, const float* __restrict__ q,
                      const float* __restrict__ v, const int* __restrict__ mem_sizes,
                      u16* __restrict__ nq) {
    __shared__ float qs[512];
    __shared__ float vs[512];
    __shared__ float sc[128];
    __shared__ float ns[128];
    int bt = blockIdx.x;
    int b = bt >> 5;
    int tid = threadIdx.x;
    qs[tid] = q[bt * 512 + tid];
    qs[tid + 256] = q[bt * 512 + 256 + tid];
    vs[tid] = v[tid];
    vs[tid + 256] = v[tid + 256];
    __syncthreads();
    int lane = tid & 63, w = tid >> 6;
    int h0 = lane * 8;
    float qv[8], vv[8];
#pragma unroll
    for (int i = 0; i < 8; ++i) { qv[i] = qs[h0 + i]; vv[i] = vs[h0 + i]; }
    const u16* fb = feat + (size_t)b * 128 * 512;
    for (int i = 0; i < 32; ++i) {
        int n = w * 32 + i;
        uint4 fv = *(const uint4*)(fb + n * 512 + h0);
        float fr[8];
        fr[0] = b2f((u16)(fv.x & 0xFFFF)); fr[1] = b2f((u16)(fv.x >> 16));
        fr[2] = b2f((u16)(fv.y & 0xFFFF)); fr[3] = b2f((u16)(fv.y >> 16));
        fr[4] = b2f((u16)(fv.z & 0xFFFF)); fr[5] = b2f((u16)(fv.z >> 16));
        fr[6] = b2f((u16)(fv.w & 0xFFFF)); fr[7] = b2f((u16)(fv.w >> 16));
        float a = 0.f;
#pragma unroll
        for (int jj = 0; jj < 8; ++jj) a += fast_tanh(fr[jj] + qv[jj]) * vv[jj];
        for (int off = 1; off < 64; off <<= 1) a += __shfl_xor(a, off);
        if (lane == 0) sc[n] = a;
    }
    __syncthreads();
    if (tid < 64) {
        int ms = mem_sizes[b];
        float s0 = (tid < ms) ? sc[tid] : -1e30f;
        float s1 = (tid + 64 < ms) ? sc[tid + 64] : -1e30f;
        float m = fmaxf(s0, s1);
        for (int off = 1; off < 64; off <<= 1) m = fmaxf(m, __shfl_xor(m, off));
        float e0 = __expf(s0 - m), e1 = __expf(s1 - m);
        float s = e0 + e1;
        for (int off = 1; off < 64; off <<= 1) s += __shfl_xor(s, off);
        float r = fast_rcp(s);
        ns[tid] = e0 * r;
        ns[tid + 64] = e1 * r;
    }
    __syncthreads();
    float a0 = 0.f, a1 = 0.f;
    int hc = tid * 2;
    for (int n = 0; n < 128; ++n) {
        float f = ns[n];
        unsigned int pv = *(const unsigned int*)(fb + n * 512 + hc);
        a0 += f * b2f((u16)(pv & 0xFFFF));
        a1 += f * b2f((u16)(pv >> 16));
    }
    ((unsigned int*)nq)[bt * 256 + tid] = pack2(a0, a1);
}

// ---------------- final scores -> out (f32) --------------------------------
__launch_bounds__(256)
__global__ void k_score(const u16* __restrict__ feat, const float* __restrict__ q,
                        const float* __restrict__ v, float* __restrict__ outp) {
    __shared__ float qs[512];
    __shared__ float vs[512];
    __shared__ float sc[128];
    int bt = blockIdx.x;
    int b = bt >> 5;
    int tid = threadIdx.x;
    qs[tid] = q[bt * 512 + tid];
    qs[tid + 256] = q[bt * 512 + 256 + tid];
    vs[tid] = v[tid];
    vs[tid + 256] = v[tid + 256];
    __syncthreads();
    int lane = tid & 63, w = tid >> 6;
    int h0 = lane * 8;
    float qv[8], vv[8];
#pragma unroll
    for (int i = 0; i < 8; ++i) { qv[i] = qs[h0 + i]; vv[i] = vs[h0 + i]; }
    const u16* fb = feat + (size_t)b * 128 * 512;
    for (int i = 0; i < 32; ++i) {
        int n = w * 32 + i;
        uint4 fv = *(const uint4*)(fb + n * 512 + h0);
        float fr[8];
        fr[0] = b2f((u16)(fv.x & 0xFFFF)); fr[1] = b2f((u16)(fv.x >> 16));
        fr[2] = b2f((u16)(fv.y & 0xFFFF)); fr[3] = b2f((u16)(fv.y >> 16));
        fr[4] = b2f((u16)(fv.z & 0xFFFF)); fr[5] = b2f((u16)(fv.z >> 16));
        fr[6] = b2f((u16)(fv.w & 0xFFFF)); fr[7] = b2f((u16)(fv.w >> 16));
        float a = 0.f;
#pragma unroll
        for (int jj = 0; jj < 8; ++jj) a += fast_tanh(fr[jj] + qv[jj]) * vv[jj];
        for (int off = 1; off < 64; off <<= 1) a += __shfl_xor(a, off);
        if (lane == 0) sc[n] = a;
    }
    __syncthreads();
    if (tid < 128) outp[bt * 128 + tid] = sc[tid];
}

extern "C" void kernel_launch(void* const* d_in, const int* in_sizes, int n_in,
                              void* d_out, int out_size, void* d_ws, size_t ws_size,
                              hipStream_t stream) {
    (void)in_sizes; (void)n_in; (void)out_size; (void)ws_size;
    const float* attn_mem = (const float*)d_in[0];
    const int* mem_sizes = (const int*)d_in[1];
    const float* lstm_in = (const float*)d_in[2];
    const float* init_h = (const float*)d_in[3];
    const float* init_c = (const float*)d_in[4];
    const float* init_i = (const float*)d_in[5];
    const float* w_ih = (const float*)d_in[6];
    const float* w_hh = (const float*)d_in[7];
    const float* b_ih = (const float*)d_in[8];
    const float* b_hh = (const float*)d_in[9];
    const float* attn_wm = (const float*)d_in[10];
    const float* attn_wq = (const float*)d_in[11];
    const float* attn_v = (const float*)d_in[12];
    const float* hop_wm = (const float*)d_in[13];
    const float* hop_wq = (const float*)d_in[14];
    const float* hop_v = (const float*)d_in[15];
    float* out = (float*)d_out;

    char* ws = (char*)d_ws;
    size_t off = 0;
    auto alloc = [&](size_t bytes) {
        void* p = ws + off;
        off += (bytes + 255) & ~(size_t)255;
        return p;
    };
    u16* amem_bf = (u16*)alloc(4096 * 512 * 2);
    u16* xfull_bf = (u16*)alloc(1024 * 512 * 2);
    u16* wih_bf = (u16*)alloc(2048 * 512 * 2);
    u16* whh_bf = (u16*)alloc(2048 * 512 * 2);
    u16* WmT_hop = (u16*)alloc(512 * 512 * 2);
    u16* WmT_attn = (u16*)alloc(512 * 512 * 2);
    u16* WqT_hop = (u16*)alloc(512 * 512 * 2);
    u16* WqT_attn = (u16*)alloc(512 * 512 * 2);
    float* xw = (float*)alloc(1024 * 2048 * 4);
    u16* hop_feat = (u16*)alloc(4096 * 512 * 2);
    u16* attn_feat = (u16*)alloc(4096 * 512 * 2);
    char* hbuf = (char*)alloc(2 * NW * 1024);
    u32* flags = (u32*)alloc(NW * FLAG_STRIDE * 4);
    u32* ctrl = (u32*)alloc(1024);
    float* qbuf = (float*)alloc(1024 * 512 * 4);
    u16* nq = (u16*)alloc(1024 * 512 * 2);

    k_prep<<<5632, 256, 0, stream>>>(attn_mem, amem_bf, w_ih, wih_bf, w_hh, whh_bf,
                                     lstm_in, init_i, xfull_bf,
                                     attn_wm, hop_wm, hop_wq, attn_wq,
                                     WmT_attn, WmT_hop, WqT_hop, WqT_attn, flags, ctrl);
    k_xw<<<512, 256, 0, stream>>>(xfull_bf, wih_bf, xw, b_ih, b_hh);
    k_lstm6<<<256, 256, 0, stream>>>(whh_bf, xw, init_h, init_c, WqT_hop, qbuf,
                                     hbuf, flags, ctrl,
                                     amem_bf, WmT_hop, WmT_attn, hop_feat, attn_feat);
    k_hop<<<1024, 256, 0, stream>>>(hop_feat, qbuf, hop_v, mem_sizes, nq);
    k_gemm<<<dim3(8, 16), 256, 0, stream>>>(nq, WqT_attn, qbuf, 512);
    k_score<<<1024, 256, 0, stream>>>(attn_feat, qbuf, attn_v, out);
}